// Round 5
// baseline (298.186 us; speedup 1.0000x reference)
//
#include <hip/hip_runtime.h>
#include <stdint.h>

#define B_ 4
#define S_ 1001
#define SP 1008    // padded rows (63 * 16)
#define SPAD 1024  // padded t dimension (32 * 32)
#define EIN_ 256
#define EOUT_ 64
#define H_ 10
#define NCOL 640   // H*EOUT
#define NCOL3 1920
#define SCW 1048   // sc row stride in bf16 (1024 + 24 pad; breaks pow-2 bank stride)

typedef short bf16x8 __attribute__((ext_vector_type(8)));
typedef short bf16x4 __attribute__((ext_vector_type(4)));
typedef float f32x4 __attribute__((ext_vector_type(4)));

__device__ __forceinline__ unsigned short f2bf(float f) {
  unsigned u = __float_as_uint(f);
  u += 0x7FFFu + ((u >> 16) & 1u);  // RTNE (inputs finite)
  return (unsigned short)(u >> 16);
}
__device__ __forceinline__ float bf2f(unsigned short h) {
  return __uint_as_float(((unsigned)h) << 16);
}

// ---- kernel 1: fp32 -> bf16 (x padded, W concat) + mask zero-padded fp32 ----
__global__ __launch_bounds__(256) void convert_kernel(
    const float* __restrict__ x, const float* __restrict__ Wq,
    const float* __restrict__ Wk, const float* __restrict__ Wv,
    const float* __restrict__ mask, unsigned short* __restrict__ xbf,
    unsigned short* __restrict__ wbf, float* __restrict__ mpad) {
  int i = blockIdx.x * 256 + threadIdx.x;
  const int N1 = B_ * SP * EIN_;   // 1,032,192
  const int N2 = NCOL3 * EIN_;     // 491,520
  const int N3 = SP * SPAD;        // 1,032,192
  if (i < N1) {
    int b = i / (SP * EIN_);
    int rem = i % (SP * EIN_);
    int row = rem / EIN_;
    int e = rem % EIN_;
    float v = (row < S_) ? x[((size_t)(b * S_ + row)) * EIN_ + e] : 0.0f;
    xbf[i] = f2bf(v);
  } else if (i < N1 + N2) {
    int j = i - N1;
    int col = j / EIN_;
    int e = j % EIN_;
    int mat = col / NCOL;
    int hcol = col % NCOL;
    const float* W = (mat == 0) ? Wq : (mat == 1) ? Wk : Wv;
    wbf[j] = f2bf(W[(size_t)hcol * EIN_ + e]);
  } else if (i < N1 + N2 + N3) {
    int j = i - N1 - N2;
    int row = j >> 10;
    int col = j & 1023;
    mpad[j] = (row < S_ && col < S_) ? mask[(size_t)row * S_ + col] : 0.0f;
  }
}

// ---- kernel 2: projection GEMM (MFMA bf16), 6-way N split, v written transposed ----
__global__ __launch_bounds__(256, 4) void proj_kernel(
    const unsigned short* __restrict__ xbf, const unsigned short* __restrict__ wbf,
    const float* __restrict__ bq, const float* __restrict__ bk,
    const float* __restrict__ bv, unsigned short* __restrict__ qbf,
    unsigned short* __restrict__ kbf, unsigned short* __restrict__ vT) {
  int tid = threadIdx.x;
  int wv_ = tid >> 6;
  int l = tid & 63;
  int qd = l >> 4;
  int c = l & 15;
  int bid = blockIdx.x;
  int g = bid % 6;
  int t2 = bid / 6;
  int b = t2 / 63;
  int tile = t2 % 63;
  int s0 = tile * 16;

  bf16x8 af[8];
  const unsigned short* xrowp = xbf + (size_t)(b * SP + s0 + c) * EIN_;
#pragma unroll
  for (int ks = 0; ks < 8; ++ks)
    af[ks] = *(const bf16x8*)(xrowp + ks * 32 + qd * 8);

  int ntbase = g * 20 + wv_;  // this wave's nt = ntbase + it*4, it in [0,5)
  const unsigned short* wp0 = wbf + (size_t)(ntbase * 16 + c) * EIN_ + qd * 8;
  bf16x8 wf[2][8];  // double buffer
#pragma unroll
  for (int ks = 0; ks < 8; ++ks)
    wf[0][ks] = *(const bf16x8*)(wp0 + ks * 32);

#pragma unroll
  for (int it = 0; it < 5; ++it) {
    int cur = it & 1;
    if (it < 4) {
      const unsigned short* wp = wp0 + (size_t)(it + 1) * (4 * 16 * EIN_);
#pragma unroll
      for (int ks = 0; ks < 8; ++ks)
        wf[cur ^ 1][ks] = *(const bf16x8*)(wp + ks * 32);
    }
    f32x4 acc = {0.f, 0.f, 0.f, 0.f};
#pragma unroll
    for (int ks = 0; ks < 8; ++ks)
      acc = __builtin_amdgcn_mfma_f32_16x16x32_bf16(af[ks], wf[cur][ks], acc, 0, 0, 0);

    int nt = ntbase + it * 4;
    int col = nt * 16 + c;
    int mat = col / NCOL;     // uniform per iteration (16-col blocks)
    int hcol = col % NCOL;
    int hh = hcol >> 6;
    int o = hcol & 63;
    const float* bias = (mat == 0) ? bq : (mat == 1) ? bk : bv;
    float bb = bias[hcol];
    if (mat < 2) {
      unsigned short* dst = (mat == 0) ? qbf : kbf;
      size_t base = ((size_t)(b * H_ + hh)) * SPAD * EOUT_ + o;
#pragma unroll
      for (int i = 0; i < 4; ++i) {
        int srow = s0 + qd * 4 + i;
        float v = (srow < S_) ? (acc[i] + bb) : 0.0f;  // zero pad rows
        dst[base + (size_t)srow * EOUT_] = f2bf(v);
      }
    } else {
      size_t vbase = ((size_t)(b * H_ + hh)) * EOUT_ * SPAD + (size_t)o * SPAD;
#pragma unroll
      for (int i = 0; i < 4; ++i) {
        int srow = s0 + qd * 4 + i;
        float v = (srow < S_) ? (acc[i] + bb) : 0.0f;
        vT[vbase + srow] = f2bf(v);  // scattered 2B; ~16 lines/instr, 5 MB total
      }
    }
  }
}

// ---------------- kernel 3: attention (concat out + rs export) ----------------
__global__ __launch_bounds__(256, 4) void attn_kernel(
    const unsigned short* __restrict__ qbf, const unsigned short* __restrict__ kbf,
    const unsigned short* __restrict__ vT, const float* __restrict__ mpad,
    float* __restrict__ rsbuf, float* __restrict__ out) {
  __shared__ unsigned short sc[16 * SCW];
  __shared__ float rs[16];

  int tid = threadIdx.x;
  int wv_ = tid >> 6;
  int l = tid & 63;
  int qd = l >> 4;
  int c = l & 15;
  int bid = blockIdx.x;
  int b = bid / (H_ * 63);
  int rem = bid % (H_ * 63);
  int h = rem / 63;
  int tile = rem % 63;
  int s0 = tile * 16;

  if (tid < 16) rs[tid] = 0.0f;

  float* concat = out;  // [B,S,640]
  size_t bh = (size_t)(b * H_ + h);
  const unsigned short* qb = qbf + bh * SPAD * EOUT_;
  const unsigned short* kb = kbf + bh * SPAD * EOUT_;
  const unsigned short* vb = vT + bh * EOUT_ * SPAD;

  // early vT prefetch ring (independent of phases A/B; latency hides behind A)
  const unsigned short* vbase = vb + (size_t)(wv_ * 16 + c) * SPAD + qd * 8;
  bf16x8 bpre[8];
#pragma unroll
  for (int p = 0; p < 8; ++p) bpre[p] = *(const bf16x8*)(vbase + p * 32);

  // ---- phase A: scores = (Q K^T)/16 -> sc; wave wv_ owns t in [wv_*256, +256) ----
  bf16x8 aq0 = *(const bf16x8*)(qb + (size_t)(s0 + c) * EOUT_ + qd * 8);
  bf16x8 aq1 = *(const bf16x8*)(qb + (size_t)(s0 + c) * EOUT_ + 32 + qd * 8);
  const unsigned short* kbase = kb + (size_t)(wv_ * 256 + c) * EOUT_ + qd * 8;
  bf16x8 kq[4][2];  // depth-4 ring
#pragma unroll
  for (int p = 0; p < 4; ++p) {
    kq[p][0] = *(const bf16x8*)(kbase + (size_t)p * 16 * EOUT_);
    kq[p][1] = *(const bf16x8*)(kbase + (size_t)p * 16 * EOUT_ + 32);
  }
#pragma unroll
  for (int u = 0; u < 16; ++u) {
    int slot = u & 3;
    f32x4 acc = {0.f, 0.f, 0.f, 0.f};
    acc = __builtin_amdgcn_mfma_f32_16x16x32_bf16(aq0, kq[slot][0], acc, 0, 0, 0);
    acc = __builtin_amdgcn_mfma_f32_16x16x32_bf16(aq1, kq[slot][1], acc, 0, 0, 0);
    if (u < 12) {
      kq[slot][0] = *(const bf16x8*)(kbase + (size_t)(u + 4) * 16 * EOUT_);
      kq[slot][1] = *(const bf16x8*)(kbase + (size_t)(u + 4) * 16 * EOUT_ + 32);
    }
    int t0 = wv_ * 256 + u * 16;
#pragma unroll
    for (int i = 0; i < 4; ++i)
      sc[(qd * 4 + i) * SCW + t0 + c] = f2bf(acc[i] * 0.0625f);
  }
  __syncthreads();

  // ---- phase B: row-per-wave; l = exp(s)*mask (mpad pads cols>=S_ to 0) ----
#pragma unroll
  for (int rr = 0; rr < 4; ++rr) {
    int r = wv_ * 4 + rr;
    int srow = s0 + r;
    if (srow < S_) {  // wave-uniform branch
      const float* mrow = mpad + (size_t)srow * SPAD;
      f32x4 mv[4];
      bf16x4 sv[4];
#pragma unroll
      for (int ci = 0; ci < 4; ++ci) {
        int t0c = ci * 256 + 4 * l;
        mv[ci] = *(const f32x4*)(mrow + t0c);
        sv[ci] = *(const bf16x4*)&sc[r * SCW + t0c];
      }
      float nacc = 0.0f;
#pragma unroll
      for (int ci = 0; ci < 4; ++ci) {
        int t0c = ci * 256 + 4 * l;
        bf16x4 lvv;
#pragma unroll
        for (int j = 0; j < 4; ++j) {
          float e = __expf(bf2f((unsigned short)sv[ci][j]));
          float lval = e * mv[ci][j];
          nacc += lval * lval;
          lvv[j] = (short)f2bf(lval);
        }
        *(bf16x4*)&sc[r * SCW + t0c] = lvv;
      }
      nacc += __shfl_xor(nacc, 1);
      nacc += __shfl_xor(nacc, 2);
      nacc += __shfl_xor(nacc, 4);
      nacc += __shfl_xor(nacc, 8);
      nacc += __shfl_xor(nacc, 16);
      nacc += __shfl_xor(nacc, 32);
      if (l == 0) rs[r] = 1.0f / fmaxf(sqrtf(nacc), 1e-12f);
    }
  }
  __syncthreads();

  if (tid < 16) rsbuf[((size_t)bh * 63 + tile) * 16 + tid] = rs[tid];

  // ---- phase D: out = (l V) * rs[row]; rolling 8-deep vT ring ----
  f32x4 oacc = {0.f, 0.f, 0.f, 0.f};
#pragma unroll
  for (int kstep = 0; kstep < 32; ++kstep) {
    int slot = kstep & 7;
    bf16x8 afr = *(const bf16x8*)&sc[c * SCW + kstep * 32 + qd * 8];
    oacc = __builtin_amdgcn_mfma_f32_16x16x32_bf16(afr, bpre[slot], oacc, 0, 0, 0);
    if (kstep < 24) bpre[slot] = *(const bf16x8*)(vbase + (size_t)(kstep + 8) * 32);
  }
#pragma unroll
  for (int i = 0; i < 4; ++i) {
    int row = qd * 4 + i;
    int srow = s0 + row;
    if (srow < S_)
      concat[((size_t)(b * S_) + srow) * NCOL + h * EOUT_ + wv_ * 16 + c] =
          oacc[i] * rs[row];
  }
}

// ---- kernel 4: wsum[b,s,t] = mask[s,t] * sum_h rs_h[s] * exp(score_h[s,t]) ----
__global__ __launch_bounds__(256, 4) void wsum_kernel(
    const unsigned short* __restrict__ qbf, const unsigned short* __restrict__ kbf,
    const float* __restrict__ rsbuf, const float* __restrict__ mpad,
    float* __restrict__ out) {
  __shared__ float wrs[H_ * 16];
  int tid = threadIdx.x;
  int wv_ = tid >> 6;
  int l = tid & 63;
  int qd = l >> 4;
  int c = l & 15;
  int bid = blockIdx.x;
  int tchunk = bid & 3;
  int rem = bid >> 2;
  int tile = rem % 63;
  int b = rem / 63;
  int s0 = tile * 16;
  int tb = tchunk * 256 + wv_ * 64;

  if (tid < H_ * 16) {
    int h = tid >> 4, row = tid & 15;
    wrs[tid] = rsbuf[((size_t)(b * H_ + h) * 63 + tile) * 16 + row];
  }
  __syncthreads();

  float wacc[16];
#pragma unroll
  for (int i = 0; i < 16; ++i) wacc[i] = 0.0f;

  // double-buffered per-head fragments
  bf16x8 qf[2][2], kf[2][8];
  {
    const unsigned short* qb = qbf;
    const unsigned short* kb = kbf;
    size_t bh0 = (size_t)(b * H_);
    qf[0][0] = *(const bf16x8*)(qb + bh0 * SPAD * EOUT_ + (size_t)(s0 + c) * EOUT_ + qd * 8);
    qf[0][1] = *(const bf16x8*)(qb + bh0 * SPAD * EOUT_ + (size_t)(s0 + c) * EOUT_ + 32 + qd * 8);
#pragma unroll
    for (int st = 0; st < 4; ++st) {
      const unsigned short* krow =
          kb + bh0 * SPAD * EOUT_ + (size_t)(tb + st * 16 + c) * EOUT_ + qd * 8;
      kf[0][st * 2] = *(const bf16x8*)krow;
      kf[0][st * 2 + 1] = *(const bf16x8*)(krow + 32);
    }
  }

  for (int h = 0; h < H_; ++h) {
    int sl = h & 1;
    if (h < H_ - 1) {
      size_t bh1 = (size_t)(b * H_ + h + 1);
      const unsigned short* qb = qbf + bh1 * SPAD * EOUT_;
      const unsigned short* kb = kbf + bh1 * SPAD * EOUT_;
      qf[sl ^ 1][0] = *(const bf16x8*)(qb + (size_t)(s0 + c) * EOUT_ + qd * 8);
      qf[sl ^ 1][1] = *(const bf16x8*)(qb + (size_t)(s0 + c) * EOUT_ + 32 + qd * 8);
#pragma unroll
      for (int st = 0; st < 4; ++st) {
        const unsigned short* krow =
            kb + (size_t)(tb + st * 16 + c) * EOUT_ + qd * 8;
        kf[sl ^ 1][st * 2] = *(const bf16x8*)krow;
        kf[sl ^ 1][st * 2 + 1] = *(const bf16x8*)(krow + 32);
      }
    }
    f32x4 acc[4];
#pragma unroll
    for (int st = 0; st < 4; ++st) {
      f32x4 a = {0.f, 0.f, 0.f, 0.f};
      a = __builtin_amdgcn_mfma_f32_16x16x32_bf16(qf[sl][0], kf[sl][st * 2], a, 0, 0, 0);
      a = __builtin_amdgcn_mfma_f32_16x16x32_bf16(qf[sl][1], kf[sl][st * 2 + 1], a, 0, 0, 0);
      acc[st] = a;
    }
#pragma unroll
    for (int st = 0; st < 4; ++st)
#pragma unroll
      for (int i = 0; i < 4; ++i)
        wacc[st * 4 + i] += wrs[h * 16 + qd * 4 + i] * __expf(acc[st][i] * 0.0625f);
  }

  float* wsum = out + (size_t)B_ * S_ * NCOL;
#pragma unroll
  for (int st = 0; st < 4; ++st) {
    int t = tb + st * 16 + c;
#pragma unroll
    for (int i = 0; i < 4; ++i) {
      int srow = s0 + qd * 4 + i;
      if (srow < S_ && t < S_)
        wsum[((size_t)b * S_ + srow) * S_ + t] =
            wacc[st * 4 + i] * mpad[(size_t)srow * SPAD + t];
    }
  }
}

extern "C" void kernel_launch(void* const* d_in, const int* in_sizes, int n_in,
                              void* d_out, int out_size, void* d_ws, size_t ws_size,
                              hipStream_t stream) {
  const float* x = (const float*)d_in[0];
  const float* mask = (const float*)d_in[1];
  const float* Wq = (const float*)d_in[2];
  const float* bq = (const float*)d_in[3];
  const float* Wk = (const float*)d_in[4];
  const float* bk = (const float*)d_in[5];
  const float* Wv = (const float*)d_in[6];
  const float* bv = (const float*)d_in[7];
  float* out = (float*)d_out;

  char* ws = (char*)d_ws;
  const size_t NEED = 23066112;
  if (ws_size < NEED) return;  // fail cleanly rather than OOB
  unsigned short* xbf  = (unsigned short*)ws;              // 2,064,384 B
  unsigned short* wbf  = (unsigned short*)(ws + 2064384);  //   983,040 B
  unsigned short* qbf  = (unsigned short*)(ws + 3047424);  // 5,242,880 B
  unsigned short* kbf  = (unsigned short*)(ws + 8290304);  // 5,242,880 B
  unsigned short* vT   = (unsigned short*)(ws + 13533184); // 5,242,880 B
  float*          mpad = (float*)(ws + 18776064);          // 4,128,768 B
  float*          rsbuf = (float*)(ws + 22904832);         //   161,280 B

  convert_kernel<<<9984, 256, 0, stream>>>(x, Wq, Wk, Wv, mask, xbf, wbf, mpad);
  proj_kernel<<<1512, 256, 0, stream>>>(xbf, wbf, bq, bk, bv, qbf, kbf, vT);
  attn_kernel<<<2520, 256, 0, stream>>>(qbf, kbf, vT, mpad, rsbuf, out);
  wsum_kernel<<<1008, 256, 0, stream>>>(qbf, kbf, rsbuf, mpad, out);
}

// Round 6
// 273.328 us; speedup vs baseline: 1.0909x; 1.0909x over previous
//
#include <hip/hip_runtime.h>
#include <stdint.h>

#define B_ 4
#define S_ 1001
#define SP 1008    // padded rows (63 * 16)
#define SPAD 1024  // padded t dimension (32 * 32)
#define EIN_ 256
#define EOUT_ 64
#define H_ 10
#define NCOL 640   // H*EOUT
#define NCOL3 1920
#define SCW 1048   // sc row stride in bf16 (1024 + 24 pad)

typedef short bf16x8 __attribute__((ext_vector_type(8)));
typedef short bf16x4 __attribute__((ext_vector_type(4)));
typedef float f32x4 __attribute__((ext_vector_type(4)));

__device__ __forceinline__ unsigned short f2bf(float f) {
  unsigned u = __float_as_uint(f);
  u += 0x7FFFu + ((u >> 16) & 1u);  // RTNE (inputs finite)
  return (unsigned short)(u >> 16);
}
__device__ __forceinline__ float bf2f(unsigned short h) {
  return __uint_as_float(((unsigned)h) << 16);
}

// ---- kernel 1: fp32 -> bf16 (x padded, W concat) + mask zero-padded fp32 ----
__global__ __launch_bounds__(256) void convert_kernel(
    const float* __restrict__ x, const float* __restrict__ Wq,
    const float* __restrict__ Wk, const float* __restrict__ Wv,
    const float* __restrict__ mask, unsigned short* __restrict__ xbf,
    unsigned short* __restrict__ wbf, float* __restrict__ mpad) {
  int i = blockIdx.x * 256 + threadIdx.x;
  const int N1 = B_ * SP * EIN_;   // 1,032,192
  const int N2 = NCOL3 * EIN_;     // 491,520
  const int N3 = SP * SPAD;        // 1,032,192
  if (i < N1) {
    int b = i / (SP * EIN_);
    int rem = i % (SP * EIN_);
    int row = rem / EIN_;
    int e = rem % EIN_;
    float v = (row < S_) ? x[((size_t)(b * S_ + row)) * EIN_ + e] : 0.0f;
    xbf[i] = f2bf(v);
  } else if (i < N1 + N2) {
    int j = i - N1;
    int col = j / EIN_;
    int e = j % EIN_;
    int mat = col / NCOL;
    int hcol = col % NCOL;
    const float* W = (mat == 0) ? Wq : (mat == 1) ? Wk : Wv;
    wbf[j] = f2bf(W[(size_t)hcol * EIN_ + e]);
  } else if (i < N1 + N2 + N3) {
    int j = i - N1 - N2;
    int row = j >> 10;
    int col = j & 1023;
    mpad[j] = (row < S_ && col < S_) ? mask[(size_t)row * S_ + col] : 0.0f;
  }
}

// ---- kernel 2: projection GEMM (MFMA bf16), 6-way N split, row-major v ----
__global__ __launch_bounds__(256, 4) void proj_kernel(
    const unsigned short* __restrict__ xbf, const unsigned short* __restrict__ wbf,
    const float* __restrict__ bq, const float* __restrict__ bk,
    const float* __restrict__ bv, unsigned short* __restrict__ qbf,
    unsigned short* __restrict__ kbf, unsigned short* __restrict__ vrow) {
  int tid = threadIdx.x;
  int wv_ = tid >> 6;
  int l = tid & 63;
  int qd = l >> 4;
  int c = l & 15;
  int bid = blockIdx.x;
  int g = bid % 6;
  int t2 = bid / 6;
  int b = t2 / 63;
  int tile = t2 % 63;
  int s0 = tile * 16;

  bf16x8 af[8];
  const unsigned short* xrowp = xbf + (size_t)(b * SP + s0 + c) * EIN_;
#pragma unroll
  for (int ks = 0; ks < 8; ++ks)
    af[ks] = *(const bf16x8*)(xrowp + ks * 32 + qd * 8);

  int ntbase = g * 20 + wv_;  // this wave's nt = ntbase + it*4, it in [0,5)
  const unsigned short* wp0 = wbf + (size_t)(ntbase * 16 + c) * EIN_ + qd * 8;
  bf16x8 wf[2][8];  // double buffer across nt iterations
#pragma unroll
  for (int ks = 0; ks < 8; ++ks)
    wf[0][ks] = *(const bf16x8*)(wp0 + ks * 32);

#pragma unroll
  for (int it = 0; it < 5; ++it) {
    int cur = it & 1;
    if (it < 4) {
      const unsigned short* wp = wp0 + (size_t)(it + 1) * (4 * 16 * EIN_);
#pragma unroll
      for (int ks = 0; ks < 8; ++ks)
        wf[cur ^ 1][ks] = *(const bf16x8*)(wp + ks * 32);
    }
    f32x4 acc = {0.f, 0.f, 0.f, 0.f};
#pragma unroll
    for (int ks = 0; ks < 8; ++ks)
      acc = __builtin_amdgcn_mfma_f32_16x16x32_bf16(af[ks], wf[cur][ks], acc, 0, 0, 0);

    int nt = ntbase + it * 4;
    int col = nt * 16 + c;
    int mat = col / NCOL;     // uniform per iteration (16-col blocks)
    int hcol = col % NCOL;
    int hh = hcol >> 6;
    int o = hcol & 63;
    const float* bias = (mat == 0) ? bq : (mat == 1) ? bk : bv;
    float bb = bias[hcol];
    unsigned short* dst = (mat == 0) ? qbf : (mat == 1) ? kbf : vrow;
    size_t base = ((size_t)(b * H_ + hh)) * SPAD * EOUT_ + o;
#pragma unroll
    for (int i = 0; i < 4; ++i) {
      int srow = s0 + qd * 4 + i;
      float v = (srow < S_) ? (acc[i] + bb) : 0.0f;  // zero pad rows
      dst[base + (size_t)srow * EOUT_] = f2bf(v);
    }
  }
}

// ---------------- kernel 3: v [t][o] -> vT [o][t] (LDS transpose) ----------------
__global__ __launch_bounds__(256) void transpose_v(
    const unsigned short* __restrict__ vrow, unsigned short* __restrict__ vT) {
  __shared__ unsigned short tl[64 * 65];
  int bid = blockIdx.x;
  int bh = bid >> 4;
  int t0 = (bid & 15) * 64;
  int tid = threadIdx.x;
#pragma unroll
  for (int i = 0; i < 16; ++i) {
    int idx = i * 256 + tid;
    int o = idx & 63;
    int t_l = idx >> 6;
    tl[o * 65 + t_l] = vrow[((size_t)bh * SPAD + t0 + t_l) * EOUT_ + o];
  }
  __syncthreads();
#pragma unroll
  for (int i = 0; i < 16; ++i) {
    int idx = i * 256 + tid;
    int t_l = idx & 63;
    int o = idx >> 6;
    vT[((size_t)bh * EOUT_ + o) * SPAD + t0 + t_l] = tl[o * 65 + t_l];
  }
}

// ---------------- kernel 4: attention (concat out + rs export) ----------------
__global__ __launch_bounds__(256, 4) void attn_kernel(
    const unsigned short* __restrict__ qbf, const unsigned short* __restrict__ kbf,
    const unsigned short* __restrict__ vT, const float* __restrict__ mpad,
    float* __restrict__ rsbuf, float* __restrict__ out) {
  __shared__ unsigned short sc[16 * SCW];
  __shared__ float rs[16];

  int tid = threadIdx.x;
  int wv_ = tid >> 6;
  int l = tid & 63;
  int qd = l >> 4;
  int c = l & 15;
  int bid = blockIdx.x;
  int b = bid / (H_ * 63);
  int rem = bid % (H_ * 63);
  int h = rem / 63;
  int tile = rem % 63;
  int s0 = tile * 16;

  if (tid < 16) rs[tid] = 0.0f;

  float* concat = out;  // [B,S,640]
  size_t bh = (size_t)(b * H_ + h);
  const unsigned short* qb = qbf + bh * SPAD * EOUT_;
  const unsigned short* kb = kbf + bh * SPAD * EOUT_;
  const unsigned short* vb = vT + bh * EOUT_ * SPAD;

  // early vT prefetch ring (independent of phases A/B; latency hides behind A)
  const unsigned short* vbase = vb + (size_t)(wv_ * 16 + c) * SPAD + qd * 8;
  bf16x8 bpre[8];
#pragma unroll
  for (int p = 0; p < 8; ++p) bpre[p] = *(const bf16x8*)(vbase + p * 32);

  // ---- phase A: scores = (Q K^T)/16 -> sc; wave wv_ owns t in [wv_*256, +256) ----
  bf16x8 aq0 = *(const bf16x8*)(qb + (size_t)(s0 + c) * EOUT_ + qd * 8);
  bf16x8 aq1 = *(const bf16x8*)(qb + (size_t)(s0 + c) * EOUT_ + 32 + qd * 8);
  const unsigned short* kbase = kb + (size_t)(wv_ * 256 + c) * EOUT_ + qd * 8;
  bf16x8 kq[4][2];  // depth-4 ring
#pragma unroll
  for (int p = 0; p < 4; ++p) {
    kq[p][0] = *(const bf16x8*)(kbase + (size_t)p * 16 * EOUT_);
    kq[p][1] = *(const bf16x8*)(kbase + (size_t)p * 16 * EOUT_ + 32);
  }
#pragma unroll
  for (int u = 0; u < 16; ++u) {
    int slot = u & 3;
    f32x4 acc = {0.f, 0.f, 0.f, 0.f};
    acc = __builtin_amdgcn_mfma_f32_16x16x32_bf16(aq0, kq[slot][0], acc, 0, 0, 0);
    acc = __builtin_amdgcn_mfma_f32_16x16x32_bf16(aq1, kq[slot][1], acc, 0, 0, 0);
    if (u < 12) {
      kq[slot][0] = *(const bf16x8*)(kbase + (size_t)(u + 4) * 16 * EOUT_);
      kq[slot][1] = *(const bf16x8*)(kbase + (size_t)(u + 4) * 16 * EOUT_ + 32);
    }
    int t0 = wv_ * 256 + u * 16;
#pragma unroll
    for (int i = 0; i < 4; ++i)
      sc[(qd * 4 + i) * SCW + t0 + c] = f2bf(acc[i] * 0.0625f);
  }
  __syncthreads();

  // ---- phase B: row-per-wave; l = exp(s)*mask (mpad pads cols>=S_ to 0) ----
#pragma unroll
  for (int rr = 0; rr < 4; ++rr) {
    int r = wv_ * 4 + rr;
    int srow = s0 + r;
    if (srow < S_) {  // wave-uniform branch
      const float* mrow = mpad + (size_t)srow * SPAD;
      f32x4 mv[4];
      bf16x4 sv[4];
#pragma unroll
      for (int ci = 0; ci < 4; ++ci) {
        int t0c = ci * 256 + 4 * l;
        mv[ci] = *(const f32x4*)(mrow + t0c);
        sv[ci] = *(const bf16x4*)&sc[r * SCW + t0c];
      }
      float nacc = 0.0f;
#pragma unroll
      for (int ci = 0; ci < 4; ++ci) {
        int t0c = ci * 256 + 4 * l;
        bf16x4 lvv;
#pragma unroll
        for (int j = 0; j < 4; ++j) {
          float e = __expf(bf2f((unsigned short)sv[ci][j]));
          float lval = e * mv[ci][j];
          nacc += lval * lval;
          lvv[j] = (short)f2bf(lval);
        }
        *(bf16x4*)&sc[r * SCW + t0c] = lvv;
      }
      nacc += __shfl_xor(nacc, 1);
      nacc += __shfl_xor(nacc, 2);
      nacc += __shfl_xor(nacc, 4);
      nacc += __shfl_xor(nacc, 8);
      nacc += __shfl_xor(nacc, 16);
      nacc += __shfl_xor(nacc, 32);
      if (l == 0) rs[r] = 1.0f / fmaxf(sqrtf(nacc), 1e-12f);
    }
  }
  __syncthreads();

  if (tid < 16) rsbuf[((size_t)bh * 63 + tile) * 16 + tid] = rs[tid];

  // ---- phase D: out = (l V) * rs[row]; rolling 8-deep vT ring ----
  f32x4 oacc = {0.f, 0.f, 0.f, 0.f};
#pragma unroll
  for (int kstep = 0; kstep < 32; ++kstep) {
    int slot = kstep & 7;
    bf16x8 afr = *(const bf16x8*)&sc[c * SCW + kstep * 32 + qd * 8];
    oacc = __builtin_amdgcn_mfma_f32_16x16x32_bf16(afr, bpre[slot], oacc, 0, 0, 0);
    if (kstep < 24) bpre[slot] = *(const bf16x8*)(vbase + (size_t)(kstep + 8) * 32);
  }
#pragma unroll
  for (int i = 0; i < 4; ++i) {
    int row = qd * 4 + i;
    int srow = s0 + row;
    if (srow < S_)
      concat[((size_t)(b * S_) + srow) * NCOL + h * EOUT_ + wv_ * 16 + c] =
          oacc[i] * rs[row];
  }
}

// ---- kernel 5: wsum[b,s,t] = mask[s,t] * sum_h rs_h[s] * exp(score_h[s,t]) ----
// M=64 per block (4 row-tiles) x T=256 cols: fetch ~3.4x less than M=16.
// Head-serial, Q/K fragments double-buffered across heads. ~220 VGPR, 1 wave/SIMD.
__global__ __launch_bounds__(256, 1) void wsum_kernel(
    const unsigned short* __restrict__ qbf, const unsigned short* __restrict__ kbf,
    const float* __restrict__ rsbuf, const float* __restrict__ mpad,
    float* __restrict__ out) {
  __shared__ float wrs[H_ * 64];
  int tid = threadIdx.x;
  int wv_ = tid >> 6;
  int l = tid & 63;
  int qd = l >> 4;
  int c = l & 15;
  int bid = blockIdx.x;
  int tchunk = bid & 3;
  int rem = bid >> 2;
  int rg = rem & 15;
  int b = rem >> 4;
  int s0 = rg * 64;                   // block's first row
  int tb = tchunk * 256 + wv_ * 64;   // wave's first col

  // rs for 10 heads x 64 rows (tile 63 = pad rows -> rs 0)
  for (int i = tid; i < H_ * 64; i += 256) {
    int h = i >> 6;
    int row = i & 63;
    int tile = rg * 4 + (row >> 4);
    wrs[i] = (tile < 63)
                 ? rsbuf[((size_t)(b * H_ + h) * 63 + tile) * 16 + (row & 15)]
                 : 0.0f;
  }
  __syncthreads();

  float wacc[64];
#pragma unroll
  for (int i = 0; i < 64; ++i) wacc[i] = 0.0f;

  // double-buffered per-head fragments: Q 4 mt x 2, K 4 st x 2
  bf16x8 qf[2][4][2], kf[2][4][2];
  {
    size_t bh0 = (size_t)(b * H_) * SPAD * EOUT_;
#pragma unroll
    for (int mt = 0; mt < 4; ++mt) {
      const unsigned short* qrow =
          qbf + bh0 + (size_t)(s0 + mt * 16 + c) * EOUT_ + qd * 8;
      qf[0][mt][0] = *(const bf16x8*)qrow;
      qf[0][mt][1] = *(const bf16x8*)(qrow + 32);
    }
#pragma unroll
    for (int st = 0; st < 4; ++st) {
      const unsigned short* krow =
          kbf + bh0 + (size_t)(tb + st * 16 + c) * EOUT_ + qd * 8;
      kf[0][st][0] = *(const bf16x8*)krow;
      kf[0][st][1] = *(const bf16x8*)(krow + 32);
    }
  }

  for (int h = 0; h < H_; ++h) {
    int sl = h & 1;
    if (h < H_ - 1) {
      size_t bh1 = (size_t)(b * H_ + h + 1) * SPAD * EOUT_;
#pragma unroll
      for (int mt = 0; mt < 4; ++mt) {
        const unsigned short* qrow =
            qbf + bh1 + (size_t)(s0 + mt * 16 + c) * EOUT_ + qd * 8;
        qf[sl ^ 1][mt][0] = *(const bf16x8*)qrow;
        qf[sl ^ 1][mt][1] = *(const bf16x8*)(qrow + 32);
      }
#pragma unroll
      for (int st = 0; st < 4; ++st) {
        const unsigned short* krow =
            kbf + bh1 + (size_t)(tb + st * 16 + c) * EOUT_ + qd * 8;
        kf[sl ^ 1][st][0] = *(const bf16x8*)krow;
        kf[sl ^ 1][st][1] = *(const bf16x8*)(krow + 32);
      }
    }
#pragma unroll
    for (int mt = 0; mt < 4; ++mt) {
      f32x4 rsv = *(const f32x4*)&wrs[h * 64 + mt * 16 + qd * 4];
#pragma unroll
      for (int st = 0; st < 4; ++st) {
        f32x4 a = {0.f, 0.f, 0.f, 0.f};
        a = __builtin_amdgcn_mfma_f32_16x16x32_bf16(qf[sl][mt][0], kf[sl][st][0], a, 0, 0, 0);
        a = __builtin_amdgcn_mfma_f32_16x16x32_bf16(qf[sl][mt][1], kf[sl][st][1], a, 0, 0, 0);
#pragma unroll
        for (int i = 0; i < 4; ++i)
          wacc[mt * 16 + st * 4 + i] += rsv[i] * __expf(a[i] * 0.0625f);
      }
    }
  }

  float* wsum = out + (size_t)B_ * S_ * NCOL;
#pragma unroll
  for (int mt = 0; mt < 4; ++mt) {
#pragma unroll
    for (int st = 0; st < 4; ++st) {
      int t = tb + st * 16 + c;
#pragma unroll
      for (int i = 0; i < 4; ++i) {
        int srow = s0 + mt * 16 + qd * 4 + i;
        if (srow < S_ && t < S_)
          wsum[((size_t)b * S_ + srow) * S_ + t] =
              wacc[mt * 16 + st * 4 + i] * mpad[(size_t)srow * SPAD + t];
      }
    }
  }
}

extern "C" void kernel_launch(void* const* d_in, const int* in_sizes, int n_in,
                              void* d_out, int out_size, void* d_ws, size_t ws_size,
                              hipStream_t stream) {
  const float* x = (const float*)d_in[0];
  const float* mask = (const float*)d_in[1];
  const float* Wq = (const float*)d_in[2];
  const float* bq = (const float*)d_in[3];
  const float* Wk = (const float*)d_in[4];
  const float* bk = (const float*)d_in[5];
  const float* Wv = (const float*)d_in[6];
  const float* bv = (const float*)d_in[7];
  float* out = (float*)d_out;

  char* ws = (char*)d_ws;
  const size_t NEED = 28308992;
  if (ws_size < NEED) return;  // fail cleanly rather than OOB
  unsigned short* xbf  = (unsigned short*)ws;              // 2,064,384 B
  unsigned short* wbf  = (unsigned short*)(ws + 2064384);  //   983,040 B
  unsigned short* qbf  = (unsigned short*)(ws + 3047424);  // 5,242,880 B
  unsigned short* kbf  = (unsigned short*)(ws + 8290304);  // 5,242,880 B
  unsigned short* vrow = (unsigned short*)(ws + 13533184); // 5,242,880 B
  unsigned short* vT   = (unsigned short*)(ws + 18776064); // 5,242,880 B
  float*          mpad = (float*)(ws + 24018944);          // 4,128,768 B
  float*          rsbuf = (float*)(ws + 28147712);         //   161,280 B

  convert_kernel<<<9984, 256, 0, stream>>>(x, Wq, Wk, Wv, mask, xbf, wbf, mpad);
  proj_kernel<<<1512, 256, 0, stream>>>(xbf, wbf, bq, bk, bv, qbf, kbf, vrow);
  transpose_v<<<640, 256, 0, stream>>>(vrow, vT);
  attn_kernel<<<2520, 256, 0, stream>>>(qbf, kbf, vT, mpad, rsbuf, out);
  wsum_kernel<<<256, 256, 0, stream>>>(qbf, kbf, rsbuf, mpad, out);
}

// Round 7
// 261.205 us; speedup vs baseline: 1.1416x; 1.0464x over previous
//
#include <hip/hip_runtime.h>
#include <stdint.h>

#define B_ 4
#define S_ 1001
#define SP 1008    // padded rows (63 * 16)
#define SPAD 1024  // padded t dimension (32 * 32)
#define EIN_ 256
#define EOUT_ 64
#define H_ 10
#define NCOL 640   // H*EOUT
#define NCOL3 1920
#define SCW 1048   // sc row stride in bf16 (1024 + 24 pad)

typedef short bf16x8 __attribute__((ext_vector_type(8)));
typedef short bf16x4 __attribute__((ext_vector_type(4)));
typedef float f32x4 __attribute__((ext_vector_type(4)));

__device__ __forceinline__ unsigned short f2bf(float f) {
  unsigned u = __float_as_uint(f);
  u += 0x7FFFu + ((u >> 16) & 1u);  // RTNE (inputs finite)
  return (unsigned short)(u >> 16);
}
__device__ __forceinline__ float bf2f(unsigned short h) {
  return __uint_as_float(((unsigned)h) << 16);
}

// ---- kernel 1: fp32 -> bf16 (x padded, W concat, mask zero-padded bf16) ----
__global__ __launch_bounds__(256) void convert_kernel(
    const float* __restrict__ x, const float* __restrict__ Wq,
    const float* __restrict__ Wk, const float* __restrict__ Wv,
    const float* __restrict__ mask, unsigned short* __restrict__ xbf,
    unsigned short* __restrict__ wbf, unsigned short* __restrict__ mbf) {
  int i = blockIdx.x * 256 + threadIdx.x;
  const int N1 = B_ * SP * EIN_;   // 1,032,192
  const int N2 = NCOL3 * EIN_;     // 491,520
  const int N3 = SP * SPAD;        // 1,032,192
  if (i < N1) {
    int b = i / (SP * EIN_);
    int rem = i % (SP * EIN_);
    int row = rem / EIN_;
    int e = rem % EIN_;
    float v = (row < S_) ? x[((size_t)(b * S_ + row)) * EIN_ + e] : 0.0f;
    xbf[i] = f2bf(v);
  } else if (i < N1 + N2) {
    int j = i - N1;
    int col = j / EIN_;
    int e = j % EIN_;
    int mat = col / NCOL;
    int hcol = col % NCOL;
    const float* W = (mat == 0) ? Wq : (mat == 1) ? Wk : Wv;
    wbf[j] = f2bf(W[(size_t)hcol * EIN_ + e]);
  } else if (i < N1 + N2 + N3) {
    int j = i - N1 - N2;
    int row = j >> 10;
    int col = j & 1023;
    float v = (row < S_ && col < S_) ? mask[(size_t)row * S_ + col] : 0.0f;
    mbf[j] = f2bf(v);
  }
}

// ---- kernel 2: projection GEMM (MFMA bf16), M=32/block, 6-way N split ----
__global__ __launch_bounds__(256, 2) void proj_kernel(
    const unsigned short* __restrict__ xbf, const unsigned short* __restrict__ wbf,
    const float* __restrict__ bq, const float* __restrict__ bk,
    const float* __restrict__ bv, unsigned short* __restrict__ qbf,
    unsigned short* __restrict__ kbf, unsigned short* __restrict__ vrow) {
  int tid = threadIdx.x;
  int wv_ = tid >> 6;
  int l = tid & 63;
  int qd = l >> 4;
  int c = l & 15;
  int bid = blockIdx.x;
  int g = bid % 6;
  int t2 = bid / 6;
  int b = t2 >> 5;
  int rg = t2 & 31;
  int s0 = rg * 32;  // 32 rows per block; rg=31,mt=1 rows are pad (stored 0)

  bf16x8 af[2][8];  // 2 row-tiles x 8 k-steps
#pragma unroll
  for (int mt = 0; mt < 2; ++mt) {
    const unsigned short* xrowp =
        xbf + (size_t)(b * SP + s0 + mt * 16 + c) * EIN_;  // rows>=SP read ws junk; stores guarded
#pragma unroll
    for (int ks = 0; ks < 8; ++ks)
      af[mt][ks] = *(const bf16x8*)(xrowp + ks * 32 + qd * 8);
  }

  int ntbase = g * 20 + wv_;  // this wave's nt = ntbase + it*4, it in [0,5)
  const unsigned short* wp0 = wbf + (size_t)(ntbase * 16 + c) * EIN_ + qd * 8;
  bf16x8 wf[2][8];  // double buffer across nt iterations
#pragma unroll
  for (int ks = 0; ks < 8; ++ks)
    wf[0][ks] = *(const bf16x8*)(wp0 + ks * 32);

#pragma unroll
  for (int it = 0; it < 5; ++it) {
    int cur = it & 1;
    if (it < 4) {
      const unsigned short* wp = wp0 + (size_t)(it + 1) * (4 * 16 * EIN_);
#pragma unroll
      for (int ks = 0; ks < 8; ++ks)
        wf[cur ^ 1][ks] = *(const bf16x8*)(wp + ks * 32);
    }
    f32x4 acc[2] = {{0.f, 0.f, 0.f, 0.f}, {0.f, 0.f, 0.f, 0.f}};
#pragma unroll
    for (int ks = 0; ks < 8; ++ks) {
      acc[0] = __builtin_amdgcn_mfma_f32_16x16x32_bf16(af[0][ks], wf[cur][ks], acc[0], 0, 0, 0);
      acc[1] = __builtin_amdgcn_mfma_f32_16x16x32_bf16(af[1][ks], wf[cur][ks], acc[1], 0, 0, 0);
    }
    int nt = ntbase + it * 4;
    int col = nt * 16 + c;
    int mat = col / NCOL;     // uniform per iteration (16-col blocks)
    int hcol = col % NCOL;
    int hh = hcol >> 6;
    int o = hcol & 63;
    const float* bias = (mat == 0) ? bq : (mat == 1) ? bk : bv;
    float bb = bias[hcol];
    unsigned short* dst = (mat == 0) ? qbf : (mat == 1) ? kbf : vrow;
    size_t base = ((size_t)(b * H_ + hh)) * SPAD * EOUT_ + o;
#pragma unroll
    for (int mt = 0; mt < 2; ++mt) {
#pragma unroll
      for (int i = 0; i < 4; ++i) {
        int srow = s0 + mt * 16 + qd * 4 + i;  // < SPAD always
        float v = (srow < S_) ? (acc[mt][i] + bb) : 0.0f;  // zero pad rows
        dst[base + (size_t)srow * EOUT_] = f2bf(v);
      }
    }
  }
}

// ---------------- kernel 3: v [t][o] -> vT [o][t] (LDS transpose) ----------------
__global__ __launch_bounds__(256) void transpose_v(
    const unsigned short* __restrict__ vrow, unsigned short* __restrict__ vT) {
  __shared__ unsigned short tl[64 * 65];
  int bid = blockIdx.x;
  int bh = bid >> 4;
  int t0 = (bid & 15) * 64;
  int tid = threadIdx.x;
#pragma unroll
  for (int i = 0; i < 16; ++i) {
    int idx = i * 256 + tid;
    int o = idx & 63;
    int t_l = idx >> 6;
    tl[o * 65 + t_l] = vrow[((size_t)bh * SPAD + t0 + t_l) * EOUT_ + o];
  }
  __syncthreads();
#pragma unroll
  for (int i = 0; i < 16; ++i) {
    int idx = i * 256 + tid;
    int t_l = idx & 63;
    int o = idx >> 6;
    vT[((size_t)bh * EOUT_ + o) * SPAD + t0 + t_l] = tl[o * 65 + t_l];
  }
}

// ---------------- kernel 4: attention (concat out + rs export) ----------------
// bid remap: bh = bid%40, tile = bid/40 -> all 63 tiles of one (b,h) share
// bid%8, i.e. one XCD (dispatch heuristic): K/V head (256 KB) stays in its L2.
__global__ __launch_bounds__(256, 4) void attn_kernel(
    const unsigned short* __restrict__ qbf, const unsigned short* __restrict__ kbf,
    const unsigned short* __restrict__ vT, const unsigned short* __restrict__ mbf,
    float* __restrict__ rsbuf, float* __restrict__ out) {
  __shared__ unsigned short sc[16 * SCW];
  __shared__ float rs[16];

  int tid = threadIdx.x;
  int wv_ = tid >> 6;
  int l = tid & 63;
  int qd = l >> 4;
  int c = l & 15;
  int bid = blockIdx.x;
  int bhid = bid % 40;
  int tile = bid / 40;
  int b = bhid / 10;
  int h = bhid % 10;
  int s0 = tile * 16;

  if (tid < 16) rs[tid] = 0.0f;

  float* concat = out;  // [B,S,640]
  size_t bh = (size_t)(b * H_ + h);
  const unsigned short* qb = qbf + bh * SPAD * EOUT_;
  const unsigned short* kb = kbf + bh * SPAD * EOUT_;
  const unsigned short* vb = vT + bh * EOUT_ * SPAD;

  const unsigned short* vbase = vb + (size_t)(wv_ * 16 + c) * SPAD + qd * 8;
  bf16x8 bpre[8];
#pragma unroll
  for (int p = 0; p < 8; ++p) bpre[p] = *(const bf16x8*)(vbase + p * 32);

  // ---- phase A: scores = (Q K^T)/16 -> sc; wave wv_ owns t in [wv_*256, +256) ----
  bf16x8 aq0 = *(const bf16x8*)(qb + (size_t)(s0 + c) * EOUT_ + qd * 8);
  bf16x8 aq1 = *(const bf16x8*)(qb + (size_t)(s0 + c) * EOUT_ + 32 + qd * 8);
  const unsigned short* kbase = kb + (size_t)(wv_ * 256 + c) * EOUT_ + qd * 8;
  bf16x8 kq[4][2];  // depth-4 ring
#pragma unroll
  for (int p = 0; p < 4; ++p) {
    kq[p][0] = *(const bf16x8*)(kbase + (size_t)p * 16 * EOUT_);
    kq[p][1] = *(const bf16x8*)(kbase + (size_t)p * 16 * EOUT_ + 32);
  }
#pragma unroll
  for (int u = 0; u < 16; ++u) {
    int slot = u & 3;
    f32x4 acc = {0.f, 0.f, 0.f, 0.f};
    acc = __builtin_amdgcn_mfma_f32_16x16x32_bf16(aq0, kq[slot][0], acc, 0, 0, 0);
    acc = __builtin_amdgcn_mfma_f32_16x16x32_bf16(aq1, kq[slot][1], acc, 0, 0, 0);
    if (u < 12) {
      kq[slot][0] = *(const bf16x8*)(kbase + (size_t)(u + 4) * 16 * EOUT_);
      kq[slot][1] = *(const bf16x8*)(kbase + (size_t)(u + 4) * 16 * EOUT_ + 32);
    }
    int t0 = wv_ * 256 + u * 16;
#pragma unroll
    for (int i = 0; i < 4; ++i)
      sc[(qd * 4 + i) * SCW + t0 + c] = f2bf(acc[i] * 0.0625f);
  }
  __syncthreads();

  // ---- phase B: row-per-wave; l = exp(s)*mask (mbf pads cols>=S_ to 0) ----
#pragma unroll
  for (int rr = 0; rr < 4; ++rr) {
    int r = wv_ * 4 + rr;
    int srow = s0 + r;
    if (srow < S_) {  // wave-uniform branch
      const unsigned short* mrow = mbf + (size_t)srow * SPAD;
      bf16x8 mv0 = *(const bf16x8*)(mrow + 8 * l);
      bf16x8 mv1 = *(const bf16x8*)(mrow + 512 + 8 * l);
      bf16x8 sv0 = *(const bf16x8*)&sc[r * SCW + 8 * l];
      bf16x8 sv1 = *(const bf16x8*)&sc[r * SCW + 512 + 8 * l];
      float nacc = 0.0f;
      bf16x8 lv0, lv1;
#pragma unroll
      for (int j = 0; j < 8; ++j) {
        float e = __expf(bf2f((unsigned short)sv0[j]));
        float lval = e * bf2f((unsigned short)mv0[j]);
        nacc += lval * lval;
        lv0[j] = (short)f2bf(lval);
      }
#pragma unroll
      for (int j = 0; j < 8; ++j) {
        float e = __expf(bf2f((unsigned short)sv1[j]));
        float lval = e * bf2f((unsigned short)mv1[j]);
        nacc += lval * lval;
        lv1[j] = (short)f2bf(lval);
      }
      *(bf16x8*)&sc[r * SCW + 8 * l] = lv0;
      *(bf16x8*)&sc[r * SCW + 512 + 8 * l] = lv1;
      nacc += __shfl_xor(nacc, 1);
      nacc += __shfl_xor(nacc, 2);
      nacc += __shfl_xor(nacc, 4);
      nacc += __shfl_xor(nacc, 8);
      nacc += __shfl_xor(nacc, 16);
      nacc += __shfl_xor(nacc, 32);
      if (l == 0) rs[r] = 1.0f / fmaxf(sqrtf(nacc), 1e-12f);
    }
  }
  __syncthreads();

  if (tid < 16) rsbuf[((size_t)bh * 63 + tile) * 16 + tid] = rs[tid];

  // ---- phase D: out = (l V) * rs[row]; rolling 8-deep vT ring ----
  f32x4 oacc = {0.f, 0.f, 0.f, 0.f};
#pragma unroll
  for (int kstep = 0; kstep < 32; ++kstep) {
    int slot = kstep & 7;
    bf16x8 afr = *(const bf16x8*)&sc[c * SCW + kstep * 32 + qd * 8];
    oacc = __builtin_amdgcn_mfma_f32_16x16x32_bf16(afr, bpre[slot], oacc, 0, 0, 0);
    if (kstep < 24) bpre[slot] = *(const bf16x8*)(vbase + (size_t)(kstep + 8) * 32);
  }
#pragma unroll
  for (int i = 0; i < 4; ++i) {
    int row = qd * 4 + i;
    int srow = s0 + row;
    if (srow < S_)
      concat[((size_t)(b * S_) + srow) * NCOL + h * EOUT_ + wv_ * 16 + c] =
          oacc[i] * rs[row];
  }
}

// ---- kernel 5: wsum[b,s,t] = mask[s,t] * sum_h rs_h[s] * exp(score_h[s,t]) ----
// M=64 rows x T=256 cols per block; head-serial, double-buffered fragments.
// bid remap: gid = bid%16 -> (b,tchunk) pinned to one XCD for K-slice reuse.
__global__ __launch_bounds__(256, 1) void wsum_kernel(
    const unsigned short* __restrict__ qbf, const unsigned short* __restrict__ kbf,
    const float* __restrict__ rsbuf, const unsigned short* __restrict__ mbf,
    float* __restrict__ out) {
  __shared__ float wrs[H_ * 64];
  int tid = threadIdx.x;
  int wv_ = tid >> 6;
  int l = tid & 63;
  int qd = l >> 4;
  int c = l & 15;
  int bid = blockIdx.x;
  int gid = bid & 15;
  int rg = bid >> 4;
  int b = gid >> 2;
  int tchunk = gid & 3;
  int s0 = rg * 64;                   // block's first row
  int tb = tchunk * 256 + wv_ * 64;   // wave's first col

  // rs for 10 heads x 64 rows (tile 63 = pad rows -> rs 0)
  for (int i = tid; i < H_ * 64; i += 256) {
    int h = i >> 6;
    int row = i & 63;
    int tile = rg * 4 + (row >> 4);
    wrs[i] = (tile < 63)
                 ? rsbuf[((size_t)(b * H_ + h) * 63 + tile) * 16 + (row & 15)]
                 : 0.0f;
  }
  __syncthreads();

  float wacc[64];
#pragma unroll
  for (int i = 0; i < 64; ++i) wacc[i] = 0.0f;

  bf16x8 qf[2][4][2], kf[2][4][2];
  {
    size_t bh0 = (size_t)(b * H_) * SPAD * EOUT_;
#pragma unroll
    for (int mt = 0; mt < 4; ++mt) {
      const unsigned short* qrow =
          qbf + bh0 + (size_t)(s0 + mt * 16 + c) * EOUT_ + qd * 8;
      qf[0][mt][0] = *(const bf16x8*)qrow;
      qf[0][mt][1] = *(const bf16x8*)(qrow + 32);
    }
#pragma unroll
    for (int st = 0; st < 4; ++st) {
      const unsigned short* krow =
          kbf + bh0 + (size_t)(tb + st * 16 + c) * EOUT_ + qd * 8;
      kf[0][st][0] = *(const bf16x8*)krow;
      kf[0][st][1] = *(const bf16x8*)(krow + 32);
    }
  }

  for (int h = 0; h < H_; ++h) {
    int sl = h & 1;
    if (h < H_ - 1) {
      size_t bh1 = (size_t)(b * H_ + h + 1) * SPAD * EOUT_;
#pragma unroll
      for (int mt = 0; mt < 4; ++mt) {
        const unsigned short* qrow =
            qbf + bh1 + (size_t)(s0 + mt * 16 + c) * EOUT_ + qd * 8;
        qf[sl ^ 1][mt][0] = *(const bf16x8*)qrow;
        qf[sl ^ 1][mt][1] = *(const bf16x8*)(qrow + 32);
      }
#pragma unroll
      for (int st = 0; st < 4; ++st) {
        const unsigned short* krow =
            kbf + bh1 + (size_t)(tb + st * 16 + c) * EOUT_ + qd * 8;
        kf[sl ^ 1][st][0] = *(const bf16x8*)krow;
        kf[sl ^ 1][st][1] = *(const bf16x8*)(krow + 32);
      }
    }
#pragma unroll
    for (int mt = 0; mt < 4; ++mt) {
      f32x4 rsv = *(const f32x4*)&wrs[h * 64 + mt * 16 + qd * 4];
#pragma unroll
      for (int st = 0; st < 4; ++st) {
        f32x4 a = {0.f, 0.f, 0.f, 0.f};
        a = __builtin_amdgcn_mfma_f32_16x16x32_bf16(qf[sl][mt][0], kf[sl][st][0], a, 0, 0, 0);
        a = __builtin_amdgcn_mfma_f32_16x16x32_bf16(qf[sl][mt][1], kf[sl][st][1], a, 0, 0, 0);
#pragma unroll
        for (int i = 0; i < 4; ++i)
          wacc[mt * 16 + st * 4 + i] += rsv[i] * __expf(a[i] * 0.0625f);
      }
    }
  }

  float* wsum = out + (size_t)B_ * S_ * NCOL;
#pragma unroll
  for (int mt = 0; mt < 4; ++mt) {
#pragma unroll
    for (int st = 0; st < 4; ++st) {
      int t = tb + st * 16 + c;
#pragma unroll
      for (int i = 0; i < 4; ++i) {
        int srow = s0 + mt * 16 + qd * 4 + i;
        if (srow < S_ && t < S_)
          wsum[((size_t)b * S_ + srow) * S_ + t] =
              wacc[mt * 16 + st * 4 + i] * bf2f(mbf[(size_t)srow * SPAD + t]);
      }
    }
  }
}

extern "C" void kernel_launch(void* const* d_in, const int* in_sizes, int n_in,
                              void* d_out, int out_size, void* d_ws, size_t ws_size,
                              hipStream_t stream) {
  const float* x = (const float*)d_in[0];
  const float* mask = (const float*)d_in[1];
  const float* Wq = (const float*)d_in[2];
  const float* bq = (const float*)d_in[3];
  const float* Wk = (const float*)d_in[4];
  const float* bk = (const float*)d_in[5];
  const float* Wv = (const float*)d_in[6];
  const float* bv = (const float*)d_in[7];
  float* out = (float*)d_out;

  char* ws = (char*)d_ws;
  const size_t NEED = 26244608;
  if (ws_size < NEED) return;  // fail cleanly rather than OOB
  unsigned short* xbf  = (unsigned short*)ws;              // 2,064,384 B
  unsigned short* wbf  = (unsigned short*)(ws + 2064384);  //   983,040 B
  unsigned short* qbf  = (unsigned short*)(ws + 3047424);  // 5,242,880 B
  unsigned short* kbf  = (unsigned short*)(ws + 8290304);  // 5,242,880 B
  unsigned short* vrow = (unsigned short*)(ws + 13533184); // 5,242,880 B
  unsigned short* vT   = (unsigned short*)(ws + 18776064); // 5,242,880 B
  unsigned short* mbf  = (unsigned short*)(ws + 24018944); // 2,064,384 B
  float*          rsbuf = (float*)(ws + 26083328);         //   161,280 B

  convert_kernel<<<9984, 256, 0, stream>>>(x, Wq, Wk, Wv, mask, xbf, wbf, mbf);
  proj_kernel<<<768, 256, 0, stream>>>(xbf, wbf, bq, bk, bv, qbf, kbf, vrow);
  transpose_v<<<640, 256, 0, stream>>>(vrow, vT);
  attn_kernel<<<2520, 256, 0, stream>>>(qbf, kbf, vT, mbf, rsbuf, out);
  wsum_kernel<<<256, 256, 0, stream>>>(qbf, kbf, rsbuf, mbf, out);
}